// Round 7
// baseline (173.093 us; speedup 1.0000x reference)
//
#include <hip/hip_runtime.h>

#define B_DIM   4096
#define IN_DIM  4096
#define OUT_DIM 4096

typedef float floatx4 __attribute__((ext_vector_type(4)));

// Task = half-row (2048 floats = 8 KB). Tasks 0..8191 cover input,
// 8192..16383 cover weight. part[tk*64 + lane] = lane partial of task tk.
#define PART_FLOATS (16384 * 64)   // 4 MB of lane partials

__device__ __forceinline__ float sum8(const floatx4* v) {
    float s0 = 0.f, s1 = 0.f, s2 = 0.f, s3 = 0.f;
    s0 = (v[0].x + v[0].y) + (v[0].z + v[0].w);
    s1 = (v[1].x + v[1].y) + (v[1].z + v[1].w);
    s2 = (v[2].x + v[2].y) + (v[2].z + v[2].w);
    s3 = (v[3].x + v[3].y) + (v[3].z + v[3].w);
    s0 += (v[4].x + v[4].y) + (v[4].z + v[4].w);
    s1 += (v[5].x + v[5].y) + (v[5].z + v[5].w);
    s2 += (v[6].x + v[6].y) + (v[6].z + v[6].w);
    s3 += (v[7].x + v[7].y) + (v[7].z + v[7].w);
    return (s0 + s1) + (s2 + s3);
}

// K1a: steady-state pipelined read-reduce. 1024 blocks x 4 waves = 4096
// waves, 4 half-row tasks each (tk = wg + it*4096). Register double-buffer:
// next task's 8 loads are issued BEFORE consuming the current task, so the
// wave always has 8-16 x 1 KB loads in flight (waits are vmcnt(8), never a
// full drain). No shuffles in the hot loop — each lane stores its private
// partial (fire-and-forget dword store, 256 B/wave coalesced).
__global__ __launch_bounds__(256, 4) void k1a_partials(
    const float* __restrict__ input, const float* __restrict__ weight,
    float* __restrict__ part)
{
    const int wave = threadIdx.x >> 6;
    const int lane = threadIdx.x & 63;
    const int wg   = blockIdx.x * 4 + wave;          // 0 .. 4095

    // it=0,1 -> input tasks wg, wg+4096; it=2,3 -> weight tasks wg, wg+4096
    const floatx4* b0 = (const floatx4*)(input  + (size_t)wg * 2048);
    const floatx4* b1 = (const floatx4*)(input  + (size_t)(wg + 4096) * 2048);
    const floatx4* b2 = (const floatx4*)(weight + (size_t)wg * 2048);
    const floatx4* b3 = (const floatx4*)(weight + (size_t)(wg + 4096) * 2048);

    floatx4 a[8], b[8];
    #pragma unroll
    for (int k = 0; k < 8; ++k) a[k] = b0[lane + k * 64];
    #pragma unroll
    for (int k = 0; k < 8; ++k) b[k] = b1[lane + k * 64];

    part[(size_t)wg * 64 + lane] = sum8(a);                    // waits a only
    #pragma unroll
    for (int k = 0; k < 8; ++k) a[k] = b2[lane + k * 64];      // refill

    part[(size_t)(wg + 4096) * 64 + lane] = sum8(b);           // waits b only
    #pragma unroll
    for (int k = 0; k < 8; ++k) b[k] = b3[lane + k * 64];      // refill

    part[(size_t)(wg + 8192) * 64 + lane] = sum8(a);
    part[(size_t)(wg + 12288) * 64 + lane] = sum8(b);
}

// K1b: fold 128 lane-partials per row. One wave per row (2048 blocks x 4).
// Rows 0..4095 -> xs[row]; rows 4096..8191 -> wb[o] = bias[o] * sum.
__global__ __launch_bounds__(256) void k1b_combine(
    const float* __restrict__ part, const float* __restrict__ bias,
    float* __restrict__ xs, float* __restrict__ wb)
{
    const int wave = threadIdx.x >> 6;
    const int lane = threadIdx.x & 63;
    const int row  = blockIdx.x * 4 + wave;          // 0 .. 8191

    float s = part[(size_t)row * 128 + lane] + part[(size_t)row * 128 + 64 + lane];
    #pragma unroll
    for (int off = 32; off > 0; off >>= 1)
        s += __shfl_down(s, off, 64);

    if (lane == 0) {
        if (row < B_DIM) xs[row] = s;
        else             wb[row - B_DIM] = s * bias[row - B_DIM];
    }
}

// K2: pure streaming write. One block per output row; xs[b] wave-uniform,
// bias/wb (32 KB) L2-resident, nontemporal float4 stores.
__global__ __launch_bounds__(256) void k2_epilogue(
    const float* __restrict__ bias, const float* __restrict__ xs,
    const float* __restrict__ wb, float* __restrict__ out)
{
    const int b = blockIdx.x;
    const int t = threadIdx.x;
    const float xsb = xs[b];

    const floatx4* bias4 = (const floatx4*)bias;
    const floatx4* wb4   = (const floatx4*)wb;
    floatx4* out4 = (floatx4*)out + (size_t)b * (OUT_DIM / 4);

    #pragma unroll
    for (int k = 0; k < 4; ++k) {
        const int i = t + k * 256;
        const floatx4 bi = bias4[i];
        const floatx4 w  = wb4[i];
        floatx4 r;
        r.x = fmaf(xsb, bi.x, w.x);
        r.y = fmaf(xsb, bi.y, w.y);
        r.z = fmaf(xsb, bi.z, w.z);
        r.w = fmaf(xsb, bi.w, w.w);
        __builtin_nontemporal_store(r, &out4[i]);
    }
}

extern "C" void kernel_launch(void* const* d_in, const int* in_sizes, int n_in,
                              void* d_out, int out_size, void* d_ws, size_t ws_size,
                              hipStream_t stream) {
    const float* input  = (const float*)d_in[0];
    const float* weight = (const float*)d_in[1];
    const float* bias   = (const float*)d_in[2];
    float* out  = (float*)d_out;
    float* part = (float*)d_ws;                       // 4 MB lane partials
    float* xs   = part + PART_FLOATS;                 // 4096 floats
    float* wb   = xs + B_DIM;                         // 4096 floats

    k1a_partials<<<1024, 256, 0, stream>>>(input, weight, part);
    k1b_combine<<<2048, 256, 0, stream>>>(part, bias, xs, wb);
    k2_epilogue<<<B_DIM, 256, 0, stream>>>(bias, xs, wb, out);
}